// Round 9
// baseline (186.472 us; speedup 1.0000x reference)
//
#include <hip/hip_runtime.h>

namespace {

constexpr int L = 3264;
constexpr int K = 12;
constexpr int S = 8;
constexpr int B = 64;
constexpr int A = 4;
constexpr int R = 816;            // L / LOCC
constexpr int NOFF = 21;          // delays -10..10
constexpr int PEAK_STEP = L / K;  // 272
constexpr float TWO_PI = 6.28318530717958647692f;
constexpr float CINV = TWO_PI / (float)L;
constexpr int NCHUNK = (L + 255) / 256;  // 13

typedef float v2f __attribute__((ext_vector_type(2)));

__device__ __forceinline__ float2 cmul(float2 a, float2 b) {
    return make_float2(a.x * b.x - a.y * b.y, a.x * b.y + a.y * b.x);
}

__device__ __forceinline__ float rdl(float v, int d) {
    return __uint_as_float(__builtin_amdgcn_readlane(__float_as_uint(v), d));
}

// ---------------------------------------------------------------------------
// Kernel 0: phasor stream tables (all coalesced consumers).
//   phT[t][l] = e^{+i*2pi*((t-10)*l mod L)/L}   t in [0,21)   (548 KB)
//   phI[s][l] = e^{+i*2pi*(ideal_s*l mod L)/L}  s in [0,8)    (209 KB)
//   tw[j]     = e^{+i*2pi*j/L}                  j in [0,L)    (26 KB)
// ---------------------------------------------------------------------------
__global__ __launch_bounds__(256)
void k_tables(const int* __restrict__ cs, float2* __restrict__ phT,
              float2* __restrict__ phI, float2* __restrict__ tw)
{
    const int g = blockIdx.x * 256 + threadIdx.x;
    if (g < NOFF * L) {
        const int t = g / L, l = g - t * L;
        int j = ((t - 10) * l) % L; if (j < 0) j += L;   // |.| <= 32630
        float sv, cv; __sincosf(CINV * (float)j, &sv, &cv);
        phT[g] = make_float2(cv, sv);
    } else if (g < (NOFF + S) * L) {
        const int q = g - NOFF * L;
        const int s = q / L, l = q - s * L;
        const int ideal = ((K - cs[s]) % K) * PEAK_STEP;
        const int j = (ideal * l) % L;                   // <= 9.8M, int32 ok
        float sv, cv; __sincosf(CINV * (float)j, &sv, &cv);
        phI[q] = make_float2(cv, sv);
    } else if (g < (NOFF + S + 1) * L) {
        const int j = g - (NOFF + S) * L;
        float sv, cv; __sincosf(CINV * (float)j, &sv, &cv);
        tw[j] = make_float2(cv, sv);
    }
}

// ---------------------------------------------------------------------------
// Kernel 1a: one block per LS row (s,b,a) -> 2048 blocks, 512 threads.
// Group 0 (waves 0-3): bins 0-9(+dup); group 1 (waves 4-7): bins 10-20.
// Packed-f32 complex arithmetic: basis nw=(wr,wi), nc=(-wi,wr); every
// accumulate/rotate step is scalar-broadcast x float2 FMA (v_pk_fma_f32).
// Per-bin rotation steps are wave-uniform (readlane -> SGPR). Zero sincos.
// ---------------------------------------------------------------------------
__global__ __launch_bounds__(512)
void k_dft(const float* __restrict__ lsr, const float* __restrict__ lsi,
           const int* __restrict__ cs,
           const float2* __restrict__ phT, const float2* __restrict__ phI,
           const float2* __restrict__ tw, float* __restrict__ pow_out)
{
    __shared__ float2 red[8][11];

    const int row = blockIdx.x;            // sb*A + a
    const int sb = row >> 2;
    const int a = row & 3;
    const int s = sb >> 6;
    const int tid = threadIdx.x;
    const int lane = tid & 63;
    const int w = tid >> 6;                // wave 0..7
    const int gl = tid & 255;              // lane-in-group (= starting k)
    const int grp = tid >> 8;              // 0: bins 0-9, 1: bins 10-20
    const int d0 = grp ? 10 : 0;

    const int ideal = ((K - cs[s]) % K) * PEAK_STEP;
    int idx0 = ideal - 10; if (idx0 < 0) idx0 += L;    // bin0 index, nonneg

    // initial phasor w0 = e^{i*2pi*gl*(idx0+d0)/L} = phI[s][gl]*phT[d0][gl]
    const float2 w0 = cmul(phI[s * L + gl], phT[d0 * L + gl]);
    const float2 lv = tw[gl];              // bin->bin+1 factor e^{i*2pi*gl/L}

    // per-bin k-stride-256 steps e^{i*2pi*256*bin_d/L} — uniform -> SGPR
    int bidx = idx0 + d0 + (lane < 11 ? lane : 10);
    if (bidx >= L) bidx -= L;
    const int js = (256 * bidx) % L;       // <= 835K, int32 ok
    const float2 sv = tw[js];
    float sr_[11], si_[11];
    #pragma unroll
    for (int d = 0; d < 11; ++d) {
        sr_[d] = rdl(sv.x, d);
        si_[d] = rdl(sv.y, d);
    }

    v2f nw[11], nc[11], acc[11];
    {
        float cr = w0.x, ci = w0.y;
        #pragma unroll
        for (int d = 0; d < 11; ++d) {
            nw[d] = (v2f){cr, ci};
            nc[d] = (v2f){-ci, cr};
            const float nr = cr * lv.x - ci * lv.y;
            ci = cr * lv.y + ci * lv.x;
            cr = nr;
        }
    }
    #pragma unroll
    for (int d = 0; d < 11; ++d) acc[d] = (v2f){0.f, 0.f};

    const float* __restrict__ pr  = lsr + (size_t)row * L;
    const float* __restrict__ pi_ = lsi + (size_t)row * L;

    for (int it = 0; it < 12; ++it) {      // k = gl + 256*it
        const float xr = pr[gl + (it << 8)];
        const float xi = pi_[gl + (it << 8)];
        #pragma unroll
        for (int d = 0; d < 11; ++d) {
            acc[d] += nw[d] * xr + nc[d] * xi;
            const v2f t = nw[d] * sr_[d] + nc[d] * si_[d];
            nc[d] = nc[d] * sr_[d] - nw[d] * si_[d];
            nw[d] = t;
        }
    }
    if (gl < 192) {                        // tail k = gl + 3072 < 3264
        const float xr = pr[gl + 3072];
        const float xi = pi_[gl + 3072];
        #pragma unroll
        for (int d = 0; d < 11; ++d)
            acc[d] += nw[d] * xr + nc[d] * xi;
    }

    #pragma unroll
    for (int d = 0; d < 11; ++d) {
        float r = acc[d].x, im = acc[d].y;
        #pragma unroll
        for (int o = 32; o > 0; o >>= 1) {
            r  += __shfl_xor(r, o);
            im += __shfl_xor(im, o);
        }
        if (lane == 0) red[w][d] = make_float2(r, im);
    }
    __syncthreads();

    if (tid < NOFF) {
        const int d = tid;
        const int g = (d < 10) ? 0 : 1;
        const int dl = d - g * 10;
        float rr = 0.f, ii = 0.f;
        #pragma unroll
        for (int q = 0; q < 4; ++q) {
            rr += red[4 * g + q][dl].x;
            ii += red[4 * g + q][dl].y;
        }
        pow_out[sb * (NOFF * A) + d * A + a] = rr * rr + ii * ii;
    }
}

// ---------------------------------------------------------------------------
// Kernel 1b: per sb: sum antenna powers, first-max argmax (jnp semantics).
// ---------------------------------------------------------------------------
__global__ __launch_bounds__(64)
void k_argmax(const float* __restrict__ pow_in, int* __restrict__ toff_out)
{
    const int sb = blockIdx.x;
    const int lane = threadIdx.x;

    float pw = -1.f;
    if (lane < NOFF) {
        const float4 p4 = *(const float4*)(pow_in + sb * (NOFF * A) + lane * A);
        pw = p4.x + p4.y + p4.z + p4.w;
    }
    float mx = pw;
    #pragma unroll
    for (int o = 32; o > 0; o >>= 1) mx = fmaxf(mx, __shfl_xor(mx, o));
    const unsigned long long msk = __ballot(pw == mx);
    const int argd = __ffsll(msk) - 1;     // lowest lane = first max
    if (lane == 0) toff_out[sb] = argd - 10;
}

// ---------------------------------------------------------------------------
// Kernel 1c: one block per row (s,b,a): streaming OCC-demux average.
// Fully coalesced: float4 ls loads, stride-32B phasor-stream loads,
// contiguous float2 havg writes. Zero divergence, zero trig.
// ---------------------------------------------------------------------------
__global__ __launch_bounds__(256)
void k_havg(const float* __restrict__ lsr, const float* __restrict__ lsi,
            const int* __restrict__ toff_arr,
            const float2* __restrict__ phT, const float2* __restrict__ phI,
            float2* __restrict__ havg)
{
    const int row = blockIdx.x;            // sb*A + a
    const int sb = row >> 2;
    const int s = sb >> 6;
    const int tid = threadIdx.x;

    const int tf = toff_arr[sb] + 10;      // row in phT
    const float2 emp = cmul(phI[s * L + 1], phT[tf * L + 1]);  // e^{i2pi m/L}

    const float4* __restrict__ qr4 = (const float4*)(lsr + (size_t)row * L);
    const float4* __restrict__ qi4 = (const float4*)(lsi + (size_t)row * L);
    float2* __restrict__ dst = havg + (size_t)row * R;

    for (int i = tid; i < R; i += 256) {
        const float2 w2 = cmul(phI[s * L + 4 * i], phT[tf * L + 4 * i]);
        const float4 xr = qr4[i];
        const float4 xi = qi4[i];
        float wr = w2.x, wi = w2.y;
        float are, aim, nr;
        are  = xr.x * wr - xi.x * wi;  aim  = xr.x * wi + xi.x * wr;
        nr = wr * emp.x - wi * emp.y;  wi = wr * emp.y + wi * emp.x;  wr = nr;
        are += xr.y * wr - xi.y * wi;  aim += xr.y * wi + xi.y * wr;
        nr = wr * emp.x - wi * emp.y;  wi = wr * emp.y + wi * emp.x;  wr = nr;
        are += xr.z * wr - xi.z * wi;  aim += xr.z * wi + xi.z * wr;
        nr = wr * emp.x - wi * emp.y;  wi = wr * emp.y + wi * emp.x;  wr = nr;
        are += xr.w * wr - xi.w * wi;  aim += xr.w * wi + xi.w * wr;
        dst[i] = make_float2(are * 0.25f, aim * 0.25f);
    }
}

// ---------------------------------------------------------------------------
// Kernel 2: per (b,a,l). havg from workspace (two 8-B L1-shared loads per
// stream), phasors from coalesced streams. No recompute, zero trig.
// ---------------------------------------------------------------------------
__global__ __launch_bounds__(256)
void k_final(const float* __restrict__ lsr, const float* __restrict__ lsi,
             const int* __restrict__ toff_arr, const float2* __restrict__ havg,
             const float2* __restrict__ phT, const float2* __restrict__ phI,
             float* __restrict__ out)
{
    __shared__ int tfs[S];

    const int bid = blockIdx.x;
    const int chunk = bid % NCHUNK;
    const int ba = bid / NCHUNK;
    const int b = ba >> 2;
    const int a = ba & 3;
    const int tid = threadIdx.x;

    if (tid < S) tfs[tid] = toff_arr[tid * B + b] + 10;
    __syncthreads();

    const int l = chunk * 256 + tid;
    if (l >= L) return;

    float t2 = ((float)l - 1.5f) * 0.25f;
    t2 = fminf(fmaxf(t2, 0.0f), (float)(R - 1));
    const int i0 = (int)t2;
    const int i1 = min(i0 + 1, R - 1);
    const float frac = t2 - (float)i0;

    float hire[S], hiim[S], pmre[S], pmim[S], ptre[S], ptim[S];
    float rre = 0.f, rim = 0.f;

    #pragma unroll
    for (int s = 0; s < S; ++s) {
        const int tf = tfs[s];
        const size_t hb = ((size_t)(s * B + b) * A + a) * R;
        const float2 h0 = havg[hb + i0];
        const float2 h1 = havg[hb + i1];
        const float hr = h0.x * (1.f - frac) + h1.x * frac;
        const float hi = h0.y * (1.f - frac) + h1.y * frac;
        const float2 pt = phT[tf * L + l];
        const float2 wm = cmul(phI[s * L + l], pt);
        hire[s] = hr; hiim[s] = hi;
        pmre[s] = wm.x; pmim[s] = wm.y;
        ptre[s] = pt.x; ptim[s] = pt.y;
        rre += hr * wm.x + hi * wm.y;                  // h * conj(ph_m)
        rim += hi * wm.x - hr * wm.y;
    }

    const size_t off0 = ((size_t)(b * A + a)) * L + l;
    const float resre = lsr[off0] - rre;
    const float resim = lsi[off0] - rim;

    #pragma unroll
    for (int s = 0; s < S; ++s) {
        const float wre = hire[s] + resre * pmre[s] - resim * pmim[s];
        const float wim = hiim[s] + resre * pmim[s] + resim * pmre[s];
        const float fre = wre * ptre[s] + wim * ptim[s];   // * conj(ph_T)
        const float fim = wim * ptre[s] - wre * ptim[s];
        const size_t o = (((size_t)(s * B + b)) * A + a) * L + l;
        out[o] = fre;
        out[(size_t)S * B * A * L + o] = fim;
    }
}

}  // namespace

extern "C" void kernel_launch(void* const* d_in, const int* in_sizes, int n_in,
                              void* d_out, int out_size, void* d_ws, size_t ws_size,
                              hipStream_t stream) {
    (void)in_sizes; (void)n_in; (void)out_size; (void)ws_size;
    const float* lsr = (const float*)d_in[0];
    const float* lsi = (const float*)d_in[1];
    const int*   cs  = (const int*)d_in[2];
    // d_in[3] (noise_powers) unused: mmse_module is identity.

    int* toff = (int*)d_ws;                                    // 512 ints @ 0
    float2* phT  = (float2*)((char*)d_ws + 4096);              // 548352 B
    float2* phI  = (float2*)((char*)d_ws + 552448);            // 208896 B
    float2* tw   = (float2*)((char*)d_ws + 761344);            // 26112 B
    float*  powb = (float*)((char*)d_ws + 787456);             // 172032 B
    float2* havg = (float2*)((char*)d_ws + 962560);            // 13369344 B

    const int ntab = ((NOFF + S + 1) * L + 255) / 256;
    k_tables<<<ntab, 256, 0, stream>>>(cs, phT, phI, tw);
    k_dft   <<<S * B * A, 512, 0, stream>>>(lsr, lsi, cs, phT, phI, tw, powb);
    k_argmax<<<S * B, 64, 0, stream>>>(powb, toff);
    k_havg  <<<S * B * A, 256, 0, stream>>>(lsr, lsi, toff, phT, phI, havg);
    k_final <<<B * A * NCHUNK, 256, 0, stream>>>(lsr, lsi, toff, havg, phT, phI,
                                                 (float*)d_out);
}

// Round 10
// 177.661 us; speedup vs baseline: 1.0496x; 1.0496x over previous
//
#include <hip/hip_runtime.h>

namespace {

constexpr int L = 3264;
constexpr int K = 12;
constexpr int S = 8;
constexpr int B = 64;
constexpr int A = 4;
constexpr int R = 816;            // L / LOCC
constexpr int NOFF = 21;          // delays -10..10
constexpr int PEAK_STEP = L / K;  // 272
constexpr float TWO_PI = 6.28318530717958647692f;
constexpr float CINV = TWO_PI / (float)L;
constexpr int NCHUNK = (L + 255) / 256;  // 13
constexpr int HS_MAX = 66;        // max havg slice entries per chunk

__device__ __forceinline__ float2 cmul(float2 a, float2 b) {
    return make_float2(a.x * b.x - a.y * b.y, a.x * b.y + a.y * b.x);
}

// ---------------------------------------------------------------------------
// Kernel 0: phasor stream tables (all coalesced consumers).
//   phT[t][l] = e^{+i*2pi*((t-10)*l mod L)/L}   t in [0,21)   (548 KB)
//   phI[s][l] = e^{+i*2pi*(ideal_s*l mod L)/L}  s in [0,8)    (209 KB)
//   tw[j]     = e^{+i*2pi*j/L}                  j in [0,L)    (26 KB)
// ---------------------------------------------------------------------------
__global__ __launch_bounds__(256)
void k_tables(const int* __restrict__ cs, float2* __restrict__ phT,
              float2* __restrict__ phI, float2* __restrict__ tw)
{
    const int g = blockIdx.x * 256 + threadIdx.x;
    if (g < NOFF * L) {
        const int t = g / L, l = g - t * L;
        int j = ((t - 10) * l) % L; if (j < 0) j += L;   // |.| <= 32630
        float sv, cv; __sincosf(CINV * (float)j, &sv, &cv);
        phT[g] = make_float2(cv, sv);
    } else if (g < (NOFF + S) * L) {
        const int q = g - NOFF * L;
        const int s = q / L, l = q - s * L;
        const int ideal = ((K - cs[s]) % K) * PEAK_STEP;
        const int j = (ideal * l) % L;                   // <= 9.8M, int32 ok
        float sv, cv; __sincosf(CINV * (float)j, &sv, &cv);
        phI[q] = make_float2(cv, sv);
    } else if (g < (NOFF + S + 1) * L) {
        const int j = g - (NOFF + S) * L;
        float sv, cv; __sincosf(CINV * (float)j, &sv, &cv);
        tw[j] = make_float2(cv, sv);
    }
}

// ---------------------------------------------------------------------------
// Kernel 1: one block per LS row (s,b,a) -> 2048 blocks, 256 threads.
// Whole row k-slice preloaded into registers (8 float4s, one vmcnt wait).
// Bins processed SERIALLY (d-outer): only one phasor+acc pair live ->
// ~60 VGPR -> high occupancy. Rotators maintained by uniform chains:
//   wb (bin start phasor, per-lane)  *= tw[4t]   per bin
//   e  (k->k+1 within group, unif)   *= tw[1]    per bin
//   E  (group jump k->k+1024, unif)  *= tw[1024] per bin
// Zero trig, zero in-loop memory ops except the per-bin LDS reduce store.
// ---------------------------------------------------------------------------
__global__ __launch_bounds__(256, 6)
void k_dft(const float* __restrict__ lsr, const float* __restrict__ lsi,
           const int* __restrict__ cs,
           const float2* __restrict__ phT, const float2* __restrict__ phI,
           const float2* __restrict__ tw, float* __restrict__ pow_out)
{
    __shared__ float2 red[4][NOFF];

    const int row = blockIdx.x;            // sb*A + a
    const int sb = row >> 2;
    const int a = row & 3;
    const int s = sb >> 6;
    const int tid = threadIdx.x;
    const int lane = tid & 63;
    const int w = tid >> 6;                // wave 0..3

    const int ideal = ((K - cs[s]) % K) * PEAK_STEP;
    int idx0 = ideal - 10; if (idx0 < 0) idx0 += L;    // bin-0 index, in [0,L)

    // preload the entire per-thread k-slice: k = 4*tid + 1024*g (+ tail)
    const float4* __restrict__ pr4 = (const float4*)(lsr + (size_t)row * L);
    const float4* __restrict__ pi4 = (const float4*)(lsi + (size_t)row * L);
    float4 xr[4], xi[4];
    xr[0] = pr4[tid];       xi[0] = pi4[tid];
    xr[1] = pr4[tid + 256]; xi[1] = pi4[tid + 256];
    xr[2] = pr4[tid + 512]; xi[2] = pi4[tid + 512];
    xr[3] = make_float4(0.f, 0.f, 0.f, 0.f);
    xi[3] = make_float4(0.f, 0.f, 0.f, 0.f);
    if (tid < 48) { xr[3] = pr4[tid + 768]; xi[3] = pi4[tid + 768]; }

    // rotators
    const float2 e1 = tw[1];               // uniform
    const float2 E1 = tw[1024];            // uniform
    float2 e = tw[idx0];                   // e_0 = e^{i2pi*idx0/L}
    float2 E = tw[(1024 * idx0) % L];      // E_0, 1024*3263 < 2^31
    const float2 t4 = tw[4 * tid];         // per-lane bin->bin+1 factor
    float2 wb = cmul(phI[s * L + 4 * tid], phT[4 * tid]);  // phT row 0 = -10

    for (int d = 0; d < NOFF; ++d) {
        float ac_r = 0.f, ac_i = 0.f;
        float2 w2 = wb;
        #pragma unroll
        for (int g = 0; g < 4; ++g) {
            float2 u = w2;
            ac_r += xr[g].x * u.x - xi[g].x * u.y;
            ac_i += xr[g].x * u.y + xi[g].x * u.x;
            u = cmul(u, e);
            ac_r += xr[g].y * u.x - xi[g].y * u.y;
            ac_i += xr[g].y * u.y + xi[g].y * u.x;
            u = cmul(u, e);
            ac_r += xr[g].z * u.x - xi[g].z * u.y;
            ac_i += xr[g].z * u.y + xi[g].z * u.x;
            u = cmul(u, e);
            ac_r += xr[g].w * u.x - xi[g].w * u.y;
            ac_i += xr[g].w * u.y + xi[g].w * u.x;
            if (g < 3) w2 = cmul(w2, E);
        }
        #pragma unroll
        for (int o = 32; o > 0; o >>= 1) {
            ac_r += __shfl_xor(ac_r, o);
            ac_i += __shfl_xor(ac_i, o);
        }
        if (lane == 0) red[w][d] = make_float2(ac_r, ac_i);
        wb = cmul(wb, t4);
        e  = cmul(e,  e1);
        E  = cmul(E,  E1);
    }
    __syncthreads();

    if (tid < NOFF) {
        float rr = 0.f, ii = 0.f;
        #pragma unroll
        for (int q = 0; q < 4; ++q) { rr += red[q][tid].x; ii += red[q][tid].y; }
        pow_out[sb * (NOFF * A) + tid * A + a] = rr * rr + ii * ii;
    }
}

// ---------------------------------------------------------------------------
// Kernel 2: per (b,a,chunk). Fused: (1) per-(s) argmax from powb (strict >,
// ascending d => first max, jnp semantics); (2) h_avg slice (<=66 entries per
// stream) into LDS; (3) interp + residual + timing recovery, streamed out.
// ---------------------------------------------------------------------------
__global__ __launch_bounds__(256)
void k_fused(const float* __restrict__ lsr, const float* __restrict__ lsi,
             const float* __restrict__ powb,
             const float2* __restrict__ phT, const float2* __restrict__ phI,
             float* __restrict__ out)
{
    __shared__ float pw[S][NOFF];          // 672 B
    __shared__ float2 hs[S][HS_MAX];       // 4224 B
    __shared__ float2 emps[S];
    __shared__ int tfs[S];

    const int bid = blockIdx.x;
    const int chunk = bid % NCHUNK;
    const int ba = bid / NCHUNK;
    const int b = ba >> 2;
    const int a = ba & 3;
    const int tid = threadIdx.x;

    // stage 1a: antenna-summed candidate powers
    if (tid < S * NOFF) {
        const int s = tid / NOFF;
        const int d = tid - s * NOFF;
        const float4 p4 = ((const float4*)powb)[(s * B + b) * NOFF + d];
        pw[s][d] = p4.x + p4.y + p4.z + p4.w;
    }
    __syncthreads();

    // stage 1b: first-max argmax per stream + emp phasor
    if (tid < S) {
        float best = pw[tid][0]; int bd = 0;
        #pragma unroll
        for (int d = 1; d < NOFF; ++d)
            if (pw[tid][d] > best) { best = pw[tid][d]; bd = d; }
        tfs[tid] = bd;                     // row in phT (= toff + 10)
        emps[tid] = cmul(phI[tid * L + 1], phT[bd * L + 1]);  // e^{i2pi*m/L}
    }
    __syncthreads();

    // stage 2: h_avg slice for this chunk, all 8 streams
    const int imin = max(0, chunk * 64 - 1);
    const int imax = min(R - 1, chunk * 64 + 64);
    const int cnt = imax - imin + 1;       // <= 66

    for (int t = tid; t < S * HS_MAX; t += 256) {
        const int s = t / HS_MAX;
        const int ii = t - s * HS_MAX;
        if (ii < cnt) {
            const int i = imin + ii;
            const int tf = tfs[s];
            const float2 emp = emps[s];
            const size_t base = ((size_t)(s * B + b) * A + a) * L + 4 * i;
            const float4 xr = *(const float4*)(lsr + base);
            const float4 xi = *(const float4*)(lsi + base);
            const float2 w2 = cmul(phI[s * L + 4 * i], phT[tf * L + 4 * i]);
            float wr = w2.x, wi = w2.y;
            float are, aim, nr;
            are  = xr.x * wr - xi.x * wi;  aim  = xr.x * wi + xi.x * wr;
            nr = wr * emp.x - wi * emp.y;  wi = wr * emp.y + wi * emp.x;  wr = nr;
            are += xr.y * wr - xi.y * wi;  aim += xr.y * wi + xi.y * wr;
            nr = wr * emp.x - wi * emp.y;  wi = wr * emp.y + wi * emp.x;  wr = nr;
            are += xr.z * wr - xi.z * wi;  aim += xr.z * wi + xi.z * wr;
            nr = wr * emp.x - wi * emp.y;  wi = wr * emp.y + wi * emp.x;  wr = nr;
            are += xr.w * wr - xi.w * wi;  aim += xr.w * wi + xi.w * wr;
            hs[s][ii] = make_float2(are * 0.25f, aim * 0.25f);
        }
    }
    __syncthreads();

    // stage 3: per-l finish
    const int l = chunk * 256 + tid;
    if (l >= L) return;

    float t2 = ((float)l - 1.5f) * 0.25f;
    t2 = fminf(fmaxf(t2, 0.0f), (float)(R - 1));
    const int i0 = (int)t2;
    const int i1 = min(i0 + 1, R - 1);
    const float frac = t2 - (float)i0;

    float hire[S], hiim[S], pmre[S], pmim[S], ptre[S], ptim[S];
    float rre = 0.f, rim = 0.f;

    #pragma unroll
    for (int s = 0; s < S; ++s) {
        const int tf = tfs[s];
        const float2 h0 = hs[s][i0 - imin];
        const float2 h1 = hs[s][i1 - imin];
        const float hr = h0.x * (1.f - frac) + h1.x * frac;
        const float hi = h0.y * (1.f - frac) + h1.y * frac;
        const float2 pt = phT[tf * L + l];
        const float2 wm = cmul(phI[s * L + l], pt);
        hire[s] = hr; hiim[s] = hi;
        pmre[s] = wm.x; pmim[s] = wm.y;
        ptre[s] = pt.x; ptim[s] = pt.y;
        rre += hr * wm.x + hi * wm.y;                  // h * conj(ph_m)
        rim += hi * wm.x - hr * wm.y;
    }

    const size_t off0 = ((size_t)(b * A + a)) * L + l;
    const float resre = lsr[off0] - rre;
    const float resim = lsi[off0] - rim;

    #pragma unroll
    for (int s = 0; s < S; ++s) {
        const float wre = hire[s] + resre * pmre[s] - resim * pmim[s];
        const float wim = hiim[s] + resre * pmim[s] + resim * pmre[s];
        const float fre = wre * ptre[s] + wim * ptim[s];   // * conj(ph_T)
        const float fim = wim * ptre[s] - wre * ptim[s];
        const size_t o = (((size_t)(s * B + b)) * A + a) * L + l;
        out[o] = fre;
        out[(size_t)S * B * A * L + o] = fim;
    }
}

}  // namespace

extern "C" void kernel_launch(void* const* d_in, const int* in_sizes, int n_in,
                              void* d_out, int out_size, void* d_ws, size_t ws_size,
                              hipStream_t stream) {
    (void)in_sizes; (void)n_in; (void)out_size; (void)ws_size;
    const float* lsr = (const float*)d_in[0];
    const float* lsi = (const float*)d_in[1];
    const int*   cs  = (const int*)d_in[2];
    // d_in[3] (noise_powers) unused: mmse_module is identity.

    float2* phT  = (float2*)((char*)d_ws + 4096);              // 548352 B
    float2* phI  = (float2*)((char*)d_ws + 552448);            // 208896 B
    float2* tw   = (float2*)((char*)d_ws + 761344);            // 26112 B
    float*  powb = (float*)((char*)d_ws + 787456);             // 172032 B

    const int ntab = ((NOFF + S + 1) * L + 255) / 256;
    k_tables<<<ntab, 256, 0, stream>>>(cs, phT, phI, tw);
    k_dft   <<<S * B * A, 256, 0, stream>>>(lsr, lsi, cs, phT, phI, tw, powb);
    k_fused <<<B * A * NCHUNK, 256, 0, stream>>>(lsr, lsi, powb, phT, phI,
                                                 (float*)d_out);
}